// Round 1
// baseline (454.046 us; speedup 1.0000x reference)
//
#include <hip/hip_runtime.h>
#include <cstdint>
#include <cstddef>

#define THREADS 256

typedef float f32x4 __attribute__((ext_vector_type(4)));
typedef __bf16 bf16x8 __attribute__((ext_vector_type(8)));
typedef __bf16 bf16x4 __attribute__((ext_vector_type(4)));

// ---------- async global->LDS, 16B per lane, wave-uniform LDS base ----------
__device__ __forceinline__ void gload_lds16(const void* g, void* l) {
    auto gp = (const __attribute__((address_space(1))) unsigned int*)(unsigned long long)(uintptr_t)g;
    auto lp = (__attribute__((address_space(3))) unsigned int*)(unsigned int)(uintptr_t)l;
    __builtin_amdgcn_global_load_lds(gp, lp, 16, 0, 0);
}

// ---------- zero the gamma scratch (16 uints) ----------
__global__ void zero_gamma(unsigned int* p) {
    if (threadIdx.x < 16) p[threadIdx.x] = 0u;
}

// ---------- group-wise sign binarization of W (n_out x K), 5 groups ----------
// block g in [0,4]: group g. block 5: zero the leftover rows.
__global__ void binarize_w(const float* __restrict__ W, __bf16* __restrict__ Wb,
                           int n_out, int K) {
    const int g = blockIdx.x;
    const int gs = n_out / 5;
    const int tid = threadIdx.x;
    if (g == 5) {
        const int start = 5 * gs * K;
        const int end = n_out * K;
        for (int i = start + tid; i < end; i += THREADS) Wb[i] = (__bf16)0.f;
        return;
    }
    const float* wg = W + (size_t)g * gs * K;
    __bf16* og = Wb + (size_t)g * gs * K;
    const int n = gs * K;
    float s = 0.f;
    for (int i = tid; i < n; i += THREADS) s += wg[i];
    __shared__ float red[THREADS];
    red[tid] = s;
    __syncthreads();
    for (int off = THREADS / 2; off > 0; off >>= 1) {
        if (tid < off) red[tid] += red[tid + off];
        __syncthreads();
    }
    const float mean = red[0] / (float)n;
    for (int i = tid; i < n; i += THREADS) {
        const float z = wg[i] - mean;
        og[i] = (__bf16)((z > 0.f) ? 1.f : ((z < 0.f) ? -1.f : 0.f));
    }
}

// ---------- f32 -> bf16 vectorized convert ----------
__global__ void cvt_f32_bf16(const float* __restrict__ in, __bf16* __restrict__ ot, int n4) {
    int i = blockIdx.x * blockDim.x + threadIdx.x;
    if (i >= n4) return;
    f32x4 v = *reinterpret_cast<const f32x4*>(in + 4 * (size_t)i);
    bf16x4 o;
    o[0] = (__bf16)v[0]; o[1] = (__bf16)v[1]; o[2] = (__bf16)v[2]; o[3] = (__bf16)v[3];
    *reinterpret_cast<bf16x4*>(ot + 4 * (size_t)i) = o;
}

// ---------- BF16 GEMM, B^T input: Y[m,n] = sum_k A[m,k]*Bw[n,k] + bias[n] ----------
// BM=BN=128, BK=64, 4 waves, 16x16x32 MFMA, m97-style 2-barrier loop.
// Epilogue: per-group (4096 rows) absmax via block-reduce + atomicMax(float bits).
template<int OUT_BF16>
__global__ __launch_bounds__(256, 2)
void gemm_bt(const __bf16* __restrict__ A, const __bf16* __restrict__ Bw,
             const float* __restrict__ bias, void* __restrict__ outp,
             unsigned int* __restrict__ gmax, int M, int N, int K) {
    constexpr int BM = 128, BN = 128, BK = 64;
    __shared__ __attribute__((aligned(16))) __bf16 As[BM * BK];
    __shared__ __attribute__((aligned(16))) __bf16 Bs[BN * BK];
    __shared__ float wredmax[4];

    const int tid = threadIdx.x;
    const int wave = tid >> 6;
    const int lane = tid & 63;
    const int l15 = lane & 15;
    const int l4 = lane >> 4;
    const int wr = wave >> 1;   // wave tile row (0..1)
    const int wc = wave & 1;    // wave tile col (0..1)

    const int bn = blockIdx.x;
    const int bm = blockIdx.y;

    const __bf16* Ab = A + (size_t)bm * BM * K;
    const __bf16* Bb = Bw + (size_t)bn * BN * K;

    const int srow = lane >> 3;       // 0..7 row within an 8-row band
    const int scol = (lane & 7) * 8;  // bf16 column offset (8 elems = 16B)

    f32x4 acc[4][4];
#pragma unroll
    for (int m = 0; m < 4; ++m)
#pragma unroll
        for (int n = 0; n < 4; ++n)
            acc[m][n] = f32x4{0.f, 0.f, 0.f, 0.f};

    for (int k0 = 0; k0 < K; k0 += BK) {
#pragma unroll
        for (int i = 0; i < 4; ++i) {
            const int rb = i * 32 + wave * 8;   // 8-row band base
            gload_lds16(Ab + (size_t)(rb + srow) * K + k0 + scol, &As[rb * BK]);
            gload_lds16(Bb + (size_t)(rb + srow) * K + k0 + scol, &Bs[rb * BK]);
        }
        __syncthreads();   // compiler emits vmcnt(0) drain before s_barrier
#pragma unroll
        for (int kk = 0; kk < BK; kk += 32) {
            bf16x8 af[4], bfv[4];
#pragma unroll
            for (int m = 0; m < 4; ++m)
                af[m] = *reinterpret_cast<const bf16x8*>(
                    &As[(wr * 64 + m * 16 + l15) * BK + kk + l4 * 8]);
#pragma unroll
            for (int n = 0; n < 4; ++n)
                bfv[n] = *reinterpret_cast<const bf16x8*>(
                    &Bs[(wc * 64 + n * 16 + l15) * BK + kk + l4 * 8]);
#pragma unroll
            for (int m = 0; m < 4; ++m)
#pragma unroll
                for (int n = 0; n < 4; ++n)
                    acc[m][n] = __builtin_amdgcn_mfma_f32_16x16x32_bf16(
                        af[m], bfv[n], acc[m][n], 0, 0, 0);
        }
        __syncthreads();
    }

    // epilogue: bias add, store, group absmax
    const int row0 = bm * BM + wr * 64 + l4 * 4;
    const int col0 = bn * BN + wc * 64 + l15;
    float lmax = 0.f;
#pragma unroll
    for (int n = 0; n < 4; ++n) {
        const int col = col0 + n * 16;
        const float bv = bias[col];
#pragma unroll
        for (int m = 0; m < 4; ++m) {
#pragma unroll
            for (int r = 0; r < 4; ++r) {
                const int row = row0 + m * 16 + r;
                const float v = acc[m][n][r] + bv;
                lmax = fmaxf(lmax, fabsf(v));
                if (OUT_BF16) ((__bf16*)outp)[(size_t)row * N + col] = (__bf16)v;
                else          ((float*)outp)[(size_t)row * N + col] = v;
            }
        }
    }
#pragma unroll
    for (int off = 32; off > 0; off >>= 1)
        lmax = fmaxf(lmax, __shfl_down(lmax, off, 64));
    if (lane == 0) wredmax[wave] = lmax;
    __syncthreads();
    if (tid == 0) {
        const float bmax = fmaxf(fmaxf(wredmax[0], wredmax[1]),
                                 fmaxf(wredmax[2], wredmax[3]));
        atomicMax(gmax + (bm * BM) / 4096, __float_as_uint(bmax));
    }
}

// ---------- in-place absmax quantize + exact GELU on bf16 buffer ----------
__global__ void quant_gelu(__bf16* __restrict__ y, const unsigned int* __restrict__ gbits,
                           int perg8, int n8) {
    int i = blockIdx.x * blockDim.x + threadIdx.x;
    if (i >= n8) return;
    const int g = i / perg8;
    const float gamma = __uint_as_float(gbits[g]);
    const float s = 128.0f / (gamma + 1e-5f);
    bf16x8 v = *reinterpret_cast<const bf16x8*>(y + 8 * (size_t)i);
    bf16x8 o;
#pragma unroll
    for (int j = 0; j < 8; ++j) {
        float f = (float)v[j] * s;
        f = fminf(fmaxf(f, -128.0f + 1e-5f), 128.0f - 1e-5f);
        const float ge = 0.5f * f * (1.0f + erff(f * 0.70710678118654752f));
        o[j] = (__bf16)ge;
    }
    *reinterpret_cast<bf16x8*>(y + 8 * (size_t)i) = o;
}

// ---------- in-place absmax quantize of f32 output ----------
__global__ void final_scale(float* __restrict__ y, const unsigned int* __restrict__ gbits,
                            int perg4, int n4) {
    int i = blockIdx.x * blockDim.x + threadIdx.x;
    if (i >= n4) return;
    const int g = i / perg4;
    const float gamma = __uint_as_float(gbits[g]);
    const float s = 128.0f / (gamma + 1e-5f);
    f32x4 v = *reinterpret_cast<const f32x4*>(y + 4 * (size_t)i);
    f32x4 o;
#pragma unroll
    for (int j = 0; j < 4; ++j)
        o[j] = fminf(fmaxf(v[j] * s, -128.0f + 1e-5f), 128.0f - 1e-5f);
    *reinterpret_cast<f32x4*>(y + 4 * (size_t)i) = o;
}

extern "C" void kernel_launch(void* const* d_in, const int* in_sizes, int n_in,
                              void* d_out, int out_size, void* d_ws, size_t ws_size,
                              hipStream_t stream) {
    const float* x  = (const float*)d_in[0];   // (10,2048,384)
    const float* W1 = (const float*)d_in[1];   // (1536,384)
    const float* b1 = (const float*)d_in[2];   // (1536,)
    const float* W2 = (const float*)d_in[3];   // (384,1536)
    const float* b2 = (const float*)d_in[4];   // (384,)
    float* out = (float*)d_out;                // (10,2048,384) f32

    const int BB = 10, TT = 2048, C = 384, H = 1536;
    const int M = BB * TT;                     // 20480; group = 4096 rows

    const size_t szW1b = (size_t)H * C * 2;
    const size_t szW2b = (size_t)C * H * 2;
    const size_t szXb  = (size_t)M * C * 2;
    const size_t szY1  = (size_t)M * H * 2;

    char* p = (char*)d_ws;
    __bf16* W1b = (__bf16*)p; p += szW1b;
    __bf16* W2b = (__bf16*)p; p += szW2b;
    __bf16* xb  = (__bf16*)p; p += szXb;
    __bf16* y1  = (__bf16*)p; p += szY1;
    unsigned int* gamma = (unsigned int*)p; p += 64;   // gamma1[5], gamma2[5]
    if ((size_t)(p - (char*)d_ws) > ws_size) return;   // ws too small -> zero out stays

    zero_gamma<<<1, 64, 0, stream>>>(gamma);
    binarize_w<<<6, THREADS, 0, stream>>>(W1, W1b, H, C);
    binarize_w<<<6, THREADS, 0, stream>>>(W2, W2b, C, H);
    cvt_f32_bf16<<<(M * C / 4 + THREADS - 1) / THREADS, THREADS, 0, stream>>>(x, xb, M * C / 4);

    gemm_bt<1><<<dim3(H / 128, M / 128), THREADS, 0, stream>>>(
        xb, W1b, b1, (void*)y1, gamma, M, H, C);

    quant_gelu<<<(M * H / 8 + THREADS - 1) / THREADS, THREADS, 0, stream>>>(
        y1, gamma, (M / 5) * H / 8, M * H / 8);

    gemm_bt<0><<<dim3(C / 128, M / 128), THREADS, 0, stream>>>(
        y1, W2b, b2, (void*)out, gamma + 5, M, C, H);

    final_scale<<<(M * C / 4 + THREADS - 1) / THREADS, THREADS, 0, stream>>>(
        out, gamma + 5, (M / 5) * C / 4, M * C / 4);
}

// Round 2
// 166.665 us; speedup vs baseline: 2.7243x; 2.7243x over previous
//
#include <hip/hip_runtime.h>
#include <cstdint>
#include <cstddef>

#define THREADS 256
#define NB 8   // partial-sum blocks per group

typedef float f32x4 __attribute__((ext_vector_type(4)));
typedef __bf16 bf16x8 __attribute__((ext_vector_type(8)));
typedef __bf16 bf16x4 __attribute__((ext_vector_type(4)));

// ---------- async global->LDS, 16B per lane, wave-uniform LDS base ----------
__device__ __forceinline__ void gload_lds16(const void* g, void* l) {
    auto gp = (const __attribute__((address_space(1))) unsigned int*)(unsigned long long)(uintptr_t)g;
    auto lp = (__attribute__((address_space(3))) unsigned int*)(unsigned int)(uintptr_t)l;
    __builtin_amdgcn_global_load_lds(gp, lp, 16, 0, 0);
}

// ---------- zero the gamma scratch (16 uints) ----------
__global__ void zero_gamma(unsigned int* p) {
    if (threadIdx.x < 16) p[threadIdx.x] = 0u;
}

// ---------- phase 1: per-(group,block) partial sums, deterministic ----------
// grid: (NB, 5). elems_per_group divisible by 4*NB.
__global__ void group_partial_sums(const float* __restrict__ W, float* __restrict__ partials,
                                   int elems_per_group) {
    const int g = blockIdx.y, b = blockIdx.x;
    const int tid = threadIdx.x;
    const int chunk4 = elems_per_group / (4 * NB);          // f32x4 count per block
    const float* base = W + (size_t)g * elems_per_group + (size_t)b * chunk4 * 4;
    float s = 0.f;
    for (int i = tid; i < chunk4; i += THREADS) {
        f32x4 v = *reinterpret_cast<const f32x4*>(base + 4 * (size_t)i);
        s += (v[0] + v[1]) + (v[2] + v[3]);
    }
    __shared__ float red[THREADS];
    red[tid] = s;
    __syncthreads();
    for (int off = THREADS / 2; off > 0; off >>= 1) {
        if (tid < off) red[tid] += red[tid + off];
        __syncthreads();
    }
    if (tid == 0) partials[g * NB + b] = red[0];
}

// ---------- phase 2: binarize each chunk using the group mean ----------
// grid: (NB, 6). gy==5 zeros the leftover rows [5*gs*K, n_out*K).
__global__ void binarize_apply(const float* __restrict__ W, __bf16* __restrict__ Wb,
                               const float* __restrict__ partials,
                               int elems_per_group, int tail_elems) {
    const int g = blockIdx.y, b = blockIdx.x;
    const int tid = threadIdx.x;
    if (g == 5) {
        if (b != 0) return;
        __bf16* og = Wb + (size_t)5 * elems_per_group;
        for (int i = tid; i < tail_elems; i += THREADS) og[i] = (__bf16)0.f;
        return;
    }
    float total = 0.f;
#pragma unroll
    for (int j = 0; j < NB; ++j) total += partials[g * NB + j];
    const float mean = total / (float)elems_per_group;

    const int chunk4 = elems_per_group / (4 * NB);
    const size_t off0 = (size_t)g * elems_per_group + (size_t)b * chunk4 * 4;
    const float* base = W + off0;
    __bf16* ob = Wb + off0;
    for (int i = tid; i < chunk4; i += THREADS) {
        f32x4 v = *reinterpret_cast<const f32x4*>(base + 4 * (size_t)i);
        bf16x4 o;
#pragma unroll
        for (int j = 0; j < 4; ++j) {
            const float z = v[j] - mean;
            o[j] = (__bf16)((z > 0.f) ? 1.f : ((z < 0.f) ? -1.f : 0.f));
        }
        *reinterpret_cast<bf16x4*>(ob + 4 * (size_t)i) = o;
    }
}

// ---------- f32 -> bf16 vectorized convert ----------
__global__ void cvt_f32_bf16(const float* __restrict__ in, __bf16* __restrict__ ot, int n4) {
    int i = blockIdx.x * blockDim.x + threadIdx.x;
    if (i >= n4) return;
    f32x4 v = *reinterpret_cast<const f32x4*>(in + 4 * (size_t)i);
    bf16x4 o;
    o[0] = (__bf16)v[0]; o[1] = (__bf16)v[1]; o[2] = (__bf16)v[2]; o[3] = (__bf16)v[3];
    *reinterpret_cast<bf16x4*>(ot + 4 * (size_t)i) = o;
}

// ---------- BF16 GEMM, B^T input: Y[m,n] = sum_k A[m,k]*Bw[n,k] + bias[n] ----------
template<int OUT_BF16>
__global__ __launch_bounds__(256, 2)
void gemm_bt(const __bf16* __restrict__ A, const __bf16* __restrict__ Bw,
             const float* __restrict__ bias, void* __restrict__ outp,
             unsigned int* __restrict__ gmax, int M, int N, int K) {
    constexpr int BM = 128, BN = 128, BK = 64;
    __shared__ __attribute__((aligned(16))) __bf16 As[BM * BK];
    __shared__ __attribute__((aligned(16))) __bf16 Bs[BN * BK];
    __shared__ float wredmax[4];

    const int tid = threadIdx.x;
    const int wave = tid >> 6;
    const int lane = tid & 63;
    const int l15 = lane & 15;
    const int l4 = lane >> 4;
    const int wr = wave >> 1;
    const int wc = wave & 1;

    const int bn = blockIdx.x;
    const int bm = blockIdx.y;

    const __bf16* Ab = A + (size_t)bm * BM * K;
    const __bf16* Bb = Bw + (size_t)bn * BN * K;

    const int srow = lane >> 3;       // 0..7 row within an 8-row band
    const int scol = (lane & 7) * 8;  // bf16 column offset (8 elems = 16B)

    f32x4 acc[4][4];
#pragma unroll
    for (int m = 0; m < 4; ++m)
#pragma unroll
        for (int n = 0; n < 4; ++n)
            acc[m][n] = f32x4{0.f, 0.f, 0.f, 0.f};

    for (int k0 = 0; k0 < K; k0 += BK) {
#pragma unroll
        for (int i = 0; i < 4; ++i) {
            const int rb = i * 32 + wave * 8;
            gload_lds16(Ab + (size_t)(rb + srow) * K + k0 + scol, &As[rb * BK]);
            gload_lds16(Bb + (size_t)(rb + srow) * K + k0 + scol, &Bs[rb * BK]);
        }
        __syncthreads();
#pragma unroll
        for (int kk = 0; kk < BK; kk += 32) {
            bf16x8 af[4], bfv[4];
#pragma unroll
            for (int m = 0; m < 4; ++m)
                af[m] = *reinterpret_cast<const bf16x8*>(
                    &As[(wr * 64 + m * 16 + l15) * BK + kk + l4 * 8]);
#pragma unroll
            for (int n = 0; n < 4; ++n)
                bfv[n] = *reinterpret_cast<const bf16x8*>(
                    &Bs[(wc * 64 + n * 16 + l15) * BK + kk + l4 * 8]);
#pragma unroll
            for (int m = 0; m < 4; ++m)
#pragma unroll
                for (int n = 0; n < 4; ++n)
                    acc[m][n] = __builtin_amdgcn_mfma_f32_16x16x32_bf16(
                        af[m], bfv[n], acc[m][n], 0, 0, 0);
        }
        __syncthreads();
    }

    const int row0 = bm * BM + wr * 64 + l4 * 4;
    const int col0 = bn * BN + wc * 64 + l15;
    float lmax = 0.f;
#pragma unroll
    for (int n = 0; n < 4; ++n) {
        const int col = col0 + n * 16;
        const float bv = bias[col];
#pragma unroll
        for (int m = 0; m < 4; ++m) {
#pragma unroll
            for (int r = 0; r < 4; ++r) {
                const int row = row0 + m * 16 + r;
                const float v = acc[m][n][r] + bv;
                lmax = fmaxf(lmax, fabsf(v));
                if (OUT_BF16) ((__bf16*)outp)[(size_t)row * N + col] = (__bf16)v;
                else          ((float*)outp)[(size_t)row * N + col] = v;
            }
        }
    }
#pragma unroll
    for (int off = 32; off > 0; off >>= 1)
        lmax = fmaxf(lmax, __shfl_down(lmax, off, 64));
    if (lane == 0) wredmax[wave] = lmax;
    __syncthreads();
    if (tid == 0) {
        const float bmax = fmaxf(fmaxf(wredmax[0], wredmax[1]),
                                 fmaxf(wredmax[2], wredmax[3]));
        atomicMax(gmax + (bm * BM) / 4096, __float_as_uint(bmax));
    }
}

// ---------- in-place absmax quantize + exact GELU on bf16 buffer ----------
__global__ void quant_gelu(__bf16* __restrict__ y, const unsigned int* __restrict__ gbits,
                           int perg8, int n8) {
    int i = blockIdx.x * blockDim.x + threadIdx.x;
    if (i >= n8) return;
    const int g = i / perg8;
    const float gamma = __uint_as_float(gbits[g]);
    const float s = 128.0f / (gamma + 1e-5f);
    bf16x8 v = *reinterpret_cast<const bf16x8*>(y + 8 * (size_t)i);
    bf16x8 o;
#pragma unroll
    for (int j = 0; j < 8; ++j) {
        float f = (float)v[j] * s;
        f = fminf(fmaxf(f, -128.0f + 1e-5f), 128.0f - 1e-5f);
        const float ge = 0.5f * f * (1.0f + erff(f * 0.70710678118654752f));
        o[j] = (__bf16)ge;
    }
    *reinterpret_cast<bf16x8*>(y + 8 * (size_t)i) = o;
}

// ---------- in-place absmax quantize of f32 output ----------
__global__ void final_scale(float* __restrict__ y, const unsigned int* __restrict__ gbits,
                            int perg4, int n4) {
    int i = blockIdx.x * blockDim.x + threadIdx.x;
    if (i >= n4) return;
    const int g = i / perg4;
    const float gamma = __uint_as_float(gbits[g]);
    const float s = 128.0f / (gamma + 1e-5f);
    f32x4 v = *reinterpret_cast<const f32x4*>(y + 4 * (size_t)i);
    f32x4 o;
#pragma unroll
    for (int j = 0; j < 4; ++j)
        o[j] = fminf(fmaxf(v[j] * s, -128.0f + 1e-5f), 128.0f - 1e-5f);
    *reinterpret_cast<f32x4*>(y + 4 * (size_t)i) = o;
}

extern "C" void kernel_launch(void* const* d_in, const int* in_sizes, int n_in,
                              void* d_out, int out_size, void* d_ws, size_t ws_size,
                              hipStream_t stream) {
    const float* x  = (const float*)d_in[0];   // (10,2048,384)
    const float* W1 = (const float*)d_in[1];   // (1536,384)
    const float* b1 = (const float*)d_in[2];   // (1536,)
    const float* W2 = (const float*)d_in[3];   // (384,1536)
    const float* b2 = (const float*)d_in[4];   // (384,)
    float* out = (float*)d_out;                // (10,2048,384) f32

    const int BB = 10, TT = 2048, C = 384, H = 1536;
    const int M = BB * TT;                     // 20480; act group = 4096 rows

    const int gs1 = H / 5;                     // 307 rows -> 117888 elems/group
    const int gs2 = C / 5;                     // 76 rows  -> 116736 elems/group
    const int epg1 = gs1 * C;
    const int epg2 = gs2 * H;
    const int tail1 = (H - 5 * gs1) * C;       // 384
    const int tail2 = (C - 5 * gs2) * H;       // 6144

    const size_t szW1b = (size_t)H * C * 2;
    const size_t szW2b = (size_t)C * H * 2;
    const size_t szXb  = (size_t)M * C * 2;
    const size_t szY1  = (size_t)M * H * 2;

    char* p = (char*)d_ws;
    __bf16* W1b = (__bf16*)p; p += szW1b;
    __bf16* W2b = (__bf16*)p; p += szW2b;
    __bf16* xb  = (__bf16*)p; p += szXb;
    __bf16* y1  = (__bf16*)p; p += szY1;
    unsigned int* gamma = (unsigned int*)p; p += 64;     // gamma1[5], gamma2[5]
    float* psums = (float*)p; p += 2 * 5 * NB * 4;       // partial sums W1, W2
    if ((size_t)(p - (char*)d_ws) > ws_size) return;

    zero_gamma<<<1, 64, 0, stream>>>(gamma);

    group_partial_sums<<<dim3(NB, 5), THREADS, 0, stream>>>(W1, psums, epg1);
    group_partial_sums<<<dim3(NB, 5), THREADS, 0, stream>>>(W2, psums + 5 * NB, epg2);
    binarize_apply<<<dim3(NB, 6), THREADS, 0, stream>>>(W1, W1b, psums, epg1, tail1);
    binarize_apply<<<dim3(NB, 6), THREADS, 0, stream>>>(W2, W2b, psums + 5 * NB, epg2, tail2);

    cvt_f32_bf16<<<(M * C / 4 + THREADS - 1) / THREADS, THREADS, 0, stream>>>(x, xb, M * C / 4);

    gemm_bt<1><<<dim3(H / 128, M / 128), THREADS, 0, stream>>>(
        xb, W1b, b1, (void*)y1, gamma, M, H, C);

    quant_gelu<<<(M * H / 8 + THREADS - 1) / THREADS, THREADS, 0, stream>>>(
        y1, gamma, (M / 5) * H / 8, M * H / 8);

    gemm_bt<0><<<dim3(C / 128, M / 128), THREADS, 0, stream>>>(
        y1, W2b, b2, (void*)out, gamma + 5, M, C, H);

    final_scale<<<(M * C / 4 + THREADS - 1) / THREADS, THREADS, 0, stream>>>(
        out, gamma + 5, (M / 5) * C / 4, M * C / 4);
}

// Round 3
// 153.539 us; speedup vs baseline: 2.9572x; 1.0855x over previous
//
#include <hip/hip_runtime.h>
#include <cstdint>
#include <cstddef>

#define THREADS 256
#define NB 8   // partial-sum blocks per group

typedef float f32x4 __attribute__((ext_vector_type(4)));
typedef __bf16 bf16x8 __attribute__((ext_vector_type(8)));
typedef __bf16 bf16x4 __attribute__((ext_vector_type(4)));

// ---------- async global->LDS, 16B per lane, wave-uniform LDS base ----------
__device__ __forceinline__ void gload_lds16(const void* g, void* l) {
    auto gp = (const __attribute__((address_space(1))) unsigned int*)(unsigned long long)(uintptr_t)g;
    auto lp = (__attribute__((address_space(3))) unsigned int*)(unsigned int)(uintptr_t)l;
    __builtin_amdgcn_global_load_lds(gp, lp, 16, 0, 0);
}

// ---------- zero the gamma scratch ----------
__global__ void zero_gamma(unsigned int* p) {
    if (threadIdx.x < 16) p[threadIdx.x] = 0u;
}

// ---------- phase 1: per-(group,block) partial sums, deterministic ----------
__global__ void group_partial_sums(const float* __restrict__ W, float* __restrict__ partials,
                                   int elems_per_group) {
    const int g = blockIdx.y, b = blockIdx.x;
    const int tid = threadIdx.x;
    const int chunk4 = elems_per_group / (4 * NB);
    const float* base = W + (size_t)g * elems_per_group + (size_t)b * chunk4 * 4;
    float s = 0.f;
    for (int i = tid; i < chunk4; i += THREADS) {
        f32x4 v = *reinterpret_cast<const f32x4*>(base + 4 * (size_t)i);
        s += (v[0] + v[1]) + (v[2] + v[3]);
    }
    __shared__ float red[THREADS];
    red[tid] = s;
    __syncthreads();
    for (int off = THREADS / 2; off > 0; off >>= 1) {
        if (tid < off) red[tid] += red[tid + off];
        __syncthreads();
    }
    if (tid == 0) partials[g * NB + b] = red[0];
}

// ---------- phase 2: binarize each chunk using the group mean ----------
__global__ void binarize_apply(const float* __restrict__ W, __bf16* __restrict__ Wb,
                               const float* __restrict__ partials,
                               int elems_per_group, int tail_elems) {
    const int g = blockIdx.y, b = blockIdx.x;
    const int tid = threadIdx.x;
    if (g == 5) {
        if (b != 0) return;
        __bf16* og = Wb + (size_t)5 * elems_per_group;
        for (int i = tid; i < tail_elems; i += THREADS) og[i] = (__bf16)0.f;
        return;
    }
    float total = 0.f;
#pragma unroll
    for (int j = 0; j < NB; ++j) total += partials[g * NB + j];
    const float mean = total / (float)elems_per_group;

    const int chunk4 = elems_per_group / (4 * NB);
    const size_t off0 = (size_t)g * elems_per_group + (size_t)b * chunk4 * 4;
    const float* base = W + off0;
    __bf16* ob = Wb + off0;
    for (int i = tid; i < chunk4; i += THREADS) {
        f32x4 v = *reinterpret_cast<const f32x4*>(base + 4 * (size_t)i);
        bf16x4 o;
#pragma unroll
        for (int j = 0; j < 4; ++j) {
            const float z = v[j] - mean;
            o[j] = (__bf16)((z > 0.f) ? 1.f : ((z < 0.f) ? -1.f : 0.f));
        }
        *reinterpret_cast<bf16x4*>(ob + 4 * (size_t)i) = o;
    }
}

// ---------- f32 -> bf16 vectorized convert ----------
__global__ void cvt_f32_bf16(const float* __restrict__ in, __bf16* __restrict__ ot, int n4) {
    int i = blockIdx.x * blockDim.x + threadIdx.x;
    if (i >= n4) return;
    f32x4 v = *reinterpret_cast<const f32x4*>(in + 4 * (size_t)i);
    bf16x4 o;
    o[0] = (__bf16)v[0]; o[1] = (__bf16)v[1]; o[2] = (__bf16)v[2]; o[3] = (__bf16)v[3];
    *reinterpret_cast<bf16x4*>(ot + 4 * (size_t)i) = o;
}

// ================= BF16 GEMM, B^T: Y[m,n] = sum_k A[m,k]*Bw[n,k] + bias[n] ==
// BM=256, BN_ in {256,128}, BK=64, 8 waves (2M x 4N), per-wave 128 x BN_/4.
// 2-phase prefetch (T3 min): STAGE(t+1) issued before compute(t); one
// vmcnt(0)+barrier per K-tile. LDS XOR-swizzle slot^=(row&7) on BOTH the
// staging global-source address and the ds_read address (same involution).
// XCD-aware bijective block swizzle, bm-major (A-panel L2 residency).
template<int BN_, int OUT_BF16>
__global__ __launch_bounds__(512, 2)
void gemm_bt2(const __bf16* __restrict__ A, const __bf16* __restrict__ Bw,
              const float* __restrict__ bias, void* __restrict__ outp,
              unsigned int* __restrict__ gmax, int M, int N, int K,
              int GN, int nwg) {
    constexpr int BM = 256, BK = 64;
    constexpr int NF = BN_ / 64;               // B fragments per wave
    constexpr int ABYTES = BM * BK * 2;        // 32768
    constexpr int BBYTES = BN_ * BK * 2;       // 32768 or 16384
    constexpr int AR = ABYTES / (512 * 16);    // staging rounds for A
    constexpr int BR = BBYTES / (512 * 16);    // staging rounds for B
    __shared__ __attribute__((aligned(16))) char lds[2 * (ABYTES + BBYTES)];

    const int tid = threadIdx.x;
    const int wave = tid >> 6, lane = tid & 63;
    const int l15 = lane & 15, l4 = lane >> 4;
    const int wr = wave >> 2, wc = wave & 3;

    // XCD swizzle: hw block -> contiguous orig range per XCD (nwg % 8 == 0)
    const int cpx = nwg >> 3;
    const int orig = (blockIdx.x & 7) * cpx + (blockIdx.x >> 3);
    const int bm = orig / GN, bn = orig % GN;

    const __bf16* Ab = A + (size_t)bm * BM * K;
    const __bf16* Bb = Bw + (size_t)bn * BN_ * K;
    const int NT = K / BK;

    f32x4 acc[8][NF];
#pragma unroll
    for (int m = 0; m < 8; ++m)
#pragma unroll
        for (int n = 0; n < NF; ++n)
            acc[m][n] = f32x4{0.f, 0.f, 0.f, 0.f};

    auto STAGE = [&](int t, int b) {
        const int k0 = t * BK;
        char* ab = lds + b * (ABYTES + BBYTES);
        char* bb = ab + ABYTES;
#pragma unroll
        for (int j = 0; j < AR; ++j) {
            const int q = j * 8192 + tid * 16;
            const int row = q >> 7;
            const int slot = (q >> 4) & 7;
            gload_lds16(Ab + (size_t)row * K + k0 + ((slot ^ (row & 7)) << 3), ab + q);
        }
#pragma unroll
        for (int j = 0; j < BR; ++j) {
            const int q = j * 8192 + tid * 16;
            const int row = q >> 7;
            const int slot = (q >> 4) & 7;
            gload_lds16(Bb + (size_t)row * K + k0 + ((slot ^ (row & 7)) << 3), bb + q);
        }
    };

    STAGE(0, 0);
    asm volatile("s_waitcnt vmcnt(0)" ::: "memory");
    __syncthreads();

    for (int t = 0; t < NT; ++t) {
        const int b = t & 1;
        if (t + 1 < NT) STAGE(t + 1, b ^ 1);     // prefetch before compute
        const char* ab = lds + b * (ABYTES + BBYTES);
        const char* bb = ab + ABYTES;
#pragma unroll
        for (int kk = 0; kk < BK; kk += 32) {
            const int s0 = (kk >> 3) + l4;       // 16B slot before swizzle
            bf16x8 af[8], bfv[NF];
#pragma unroll
            for (int m = 0; m < 8; ++m) {
                const int r = wr * 128 + m * 16 + l15;
                af[m] = *reinterpret_cast<const bf16x8*>(
                    ab + r * 128 + ((s0 ^ (r & 7)) << 4));
            }
#pragma unroll
            for (int n = 0; n < NF; ++n) {
                const int r = wc * (BN_ / 4) + n * 16 + l15;
                bfv[n] = *reinterpret_cast<const bf16x8*>(
                    bb + r * 128 + ((s0 ^ (r & 7)) << 4));
            }
#pragma unroll
            for (int m = 0; m < 8; ++m)
#pragma unroll
                for (int n = 0; n < NF; ++n)
                    acc[m][n] = __builtin_amdgcn_mfma_f32_16x16x32_bf16(
                        af[m], bfv[n], acc[m][n], 0, 0, 0);
        }
        asm volatile("s_waitcnt vmcnt(0)" ::: "memory");
        __syncthreads();
    }

    // epilogue: bias add, store, group absmax (4096-row groups; 4096%256==0)
    const int row0 = bm * BM + wr * 128 + l4 * 4;
    const int col0 = bn * BN_ + wc * (BN_ / 4) + l15;
    float lmax = 0.f;
#pragma unroll
    for (int n = 0; n < NF; ++n) {
        const int col = col0 + n * 16;
        const float bv = bias[col];
#pragma unroll
        for (int m = 0; m < 8; ++m) {
#pragma unroll
            for (int r = 0; r < 4; ++r) {
                const int row = row0 + m * 16 + r;
                const float v = acc[m][n][r] + bv;
                lmax = fmaxf(lmax, fabsf(v));
                if (OUT_BF16) ((__bf16*)outp)[(size_t)row * N + col] = (__bf16)v;
                else          ((float*)outp)[(size_t)row * N + col] = v;
            }
        }
    }
#pragma unroll
    for (int off = 32; off > 0; off >>= 1)
        lmax = fmaxf(lmax, __shfl_down(lmax, off, 64));
    float* wredmax = (float*)lds;   // reuse LDS (all tile reads are done)
    if (lane == 0) wredmax[wave] = lmax;
    __syncthreads();
    if (tid == 0) {
        float bmax = wredmax[0];
#pragma unroll
        for (int w = 1; w < 8; ++w) bmax = fmaxf(bmax, wredmax[w]);
        atomicMax(gmax + (bm * BM) / 4096, __float_as_uint(bmax));
    }
}

// ---------- in-place absmax quantize + exact GELU on bf16 buffer ----------
__global__ void quant_gelu(__bf16* __restrict__ y, const unsigned int* __restrict__ gbits,
                           int perg8, int n8) {
    int i = blockIdx.x * blockDim.x + threadIdx.x;
    if (i >= n8) return;
    const int g = i / perg8;
    const float gamma = __uint_as_float(gbits[g]);
    const float s = 128.0f / (gamma + 1e-5f);
    bf16x8 v = *reinterpret_cast<const bf16x8*>(y + 8 * (size_t)i);
    bf16x8 o;
#pragma unroll
    for (int j = 0; j < 8; ++j) {
        float f = (float)v[j] * s;
        f = fminf(fmaxf(f, -128.0f + 1e-5f), 128.0f - 1e-5f);
        const float ge = 0.5f * f * (1.0f + erff(f * 0.70710678118654752f));
        o[j] = (__bf16)ge;
    }
    *reinterpret_cast<bf16x8*>(y + 8 * (size_t)i) = o;
}

// ---------- in-place absmax quantize of f32 output ----------
__global__ void final_scale(float* __restrict__ y, const unsigned int* __restrict__ gbits,
                            int perg4, int n4) {
    int i = blockIdx.x * blockDim.x + threadIdx.x;
    if (i >= n4) return;
    const int g = i / perg4;
    const float gamma = __uint_as_float(gbits[g]);
    const float s = 128.0f / (gamma + 1e-5f);
    f32x4 v = *reinterpret_cast<const f32x4*>(y + 4 * (size_t)i);
    f32x4 o;
#pragma unroll
    for (int j = 0; j < 4; ++j)
        o[j] = fminf(fmaxf(v[j] * s, -128.0f + 1e-5f), 128.0f - 1e-5f);
    *reinterpret_cast<f32x4*>(y + 4 * (size_t)i) = o;
}

extern "C" void kernel_launch(void* const* d_in, const int* in_sizes, int n_in,
                              void* d_out, int out_size, void* d_ws, size_t ws_size,
                              hipStream_t stream) {
    const float* x  = (const float*)d_in[0];   // (10,2048,384)
    const float* W1 = (const float*)d_in[1];   // (1536,384)
    const float* b1 = (const float*)d_in[2];   // (1536,)
    const float* W2 = (const float*)d_in[3];   // (384,1536)
    const float* b2 = (const float*)d_in[4];   // (384,)
    float* out = (float*)d_out;                // (10,2048,384) f32

    const int BB = 10, TT = 2048, C = 384, H = 1536;
    const int M = BB * TT;                     // 20480; act group = 4096 rows

    const int gs1 = H / 5;                     // 307 rows
    const int gs2 = C / 5;                     // 76 rows
    const int epg1 = gs1 * C;
    const int epg2 = gs2 * H;
    const int tail1 = (H - 5 * gs1) * C;
    const int tail2 = (C - 5 * gs2) * H;

    const size_t szW1b = (size_t)H * C * 2;
    const size_t szW2b = (size_t)C * H * 2;
    const size_t szXb  = (size_t)M * C * 2;
    const size_t szY1  = (size_t)M * H * 2;

    char* p = (char*)d_ws;
    __bf16* W1b = (__bf16*)p; p += szW1b;
    __bf16* W2b = (__bf16*)p; p += szW2b;
    __bf16* xb  = (__bf16*)p; p += szXb;
    __bf16* y1  = (__bf16*)p; p += szY1;
    unsigned int* gamma = (unsigned int*)p; p += 64;
    float* psums = (float*)p; p += 2 * 5 * NB * 4;
    if ((size_t)(p - (char*)d_ws) > ws_size) return;

    zero_gamma<<<1, 64, 0, stream>>>(gamma);

    group_partial_sums<<<dim3(NB, 5), THREADS, 0, stream>>>(W1, psums, epg1);
    group_partial_sums<<<dim3(NB, 5), THREADS, 0, stream>>>(W2, psums + 5 * NB, epg2);
    binarize_apply<<<dim3(NB, 6), THREADS, 0, stream>>>(W1, W1b, psums, epg1, tail1);
    binarize_apply<<<dim3(NB, 6), THREADS, 0, stream>>>(W2, W2b, psums + 5 * NB, epg2, tail2);

    cvt_f32_bf16<<<(M * C / 4 + THREADS - 1) / THREADS, THREADS, 0, stream>>>(x, xb, M * C / 4);

    // GEMM1: 20480x1536x384, BM=256 BN=256 -> grid 80*6 = 480 (480%8==0)
    gemm_bt2<256, 1><<<480, 512, 0, stream>>>(
        xb, W1b, b1, (void*)y1, gamma, M, H, C, H / 256, 480);

    quant_gelu<<<(M * H / 8 + THREADS - 1) / THREADS, THREADS, 0, stream>>>(
        y1, gamma, (M / 5) * H / 8, M * H / 8);

    // GEMM2: 20480x384x1536, BM=256 BN=128 -> grid 80*3 = 240 (240%8==0)
    gemm_bt2<128, 0><<<240, 512, 0, stream>>>(
        y1, W2b, b2, (void*)out, gamma + 5, M, C, H, C / 128, 240);

    final_scale<<<(M * C / 4 + THREADS - 1) / THREADS, THREADS, 0, stream>>>(
        out, gamma + 5, (M / 5) * C / 4, M * C / 4);
}